// Round 2
// baseline (245.566 us; speedup 1.0000x reference)
//
#include <hip/hip_runtime.h>

// x [B=8, H=224, W=224, D=8, C=8] fp32 (channels innermost, DC=64),
// out [8, 8, 8, 10] fp32 = relu(sum over valid (h,w) of s-by-s max-pool) + 1.
#define BB 8
#define HH 224
#define WW 224
#define DCH 64
#define NS 10      // scales 1..10
#define SEG_OUT 55 // output columns owned per wave (64 lanes - 9 halo)
#define NSEG 5     // ceil(224 / 55)
#define STRIP 28   // output rows per h-strip
#define NSTRIP 8   // 8 * 28 = 224
#define CG 8       // channel groups (2 ch per lane, 4 waves * 2 = 8 ch per block)

__global__ void zero_kernel(float* out, int n) {
    int i = blockIdx.x * blockDim.x + threadIdx.x;
    if (i < n) out[i] = 0.0f;
}

__global__ void finalize_kernel(float* out, int n) {
    int i = blockIdx.x * blockDim.x + threadIdx.x;
    if (i < n) out[i] = fmaxf(out[i], 0.0f) + 1.0f;
}

// One wave = (b, 2-channel pair, w-segment, h-strip).
// Grid = 8 * 8 * 5 * 8 = 2560 blocks of 256 -> 10 blocks/CU, occupancy
// capped by the 32-waves/CU limit (VGPR ~50, LDS 0).
__global__ __launch_bounds__(256, 2) void pool_kernel(const float* __restrict__ x,
                                                      float* __restrict__ out) {
    const int bid = blockIdx.x;
    const int cg  = bid & (CG - 1);
    const int ws  = (bid >> 3) % NSEG;
    const int hs  = ((bid >> 3) / NSEG) % NSTRIP;
    const int b   = bid / (CG * NSEG * NSTRIP);

    const int wave = threadIdx.x >> 6;
    const int lane = threadIdx.x & 63;
    const int ch   = cg * 8 + wave * 2;       // 2 channels per lane (float2)
    const int col  = ws * SEG_OUT + lane;
    const int row0 = hs * STRIP;
    const int rend = min(row0 + STRIP + (NS - 1), HH);

    // Per-scale column-ownership mask (0/1 float used via fma; pad loads are
    // 0.0 so out-of-range lanes stay finite and contribute exactly 0).
    float m[NS];
#pragma unroll
    for (int s = 1; s <= NS; ++s)
        m[s - 1] = (lane < SEG_OUT && col <= WW - s) ? 1.0f : 0.0f;

    float prev[NS - 1][2]; // previous pyramid row, scales 1..9
    float acc[NS][2];
#pragma unroll
    for (int s = 0; s < NS - 1; ++s) { prev[s][0] = 0.0f; prev[s][1] = 0.0f; }
#pragma unroll
    for (int s = 0; s < NS; ++s) { acc[s][0] = 0.0f; acc[s][1] = 0.0f; }

    const bool colok = (col < WW);
    const float* px = x + (((size_t)(b * HH + row0) * WW + col) * DCH + ch);
    const size_t rstride = (size_t)WW * DCH;

    float2 nxt = colok ? *(const float2*)px : make_float2(0.f, 0.f);

    for (int h = row0; h < rend; ++h) {
        float cp[2] = {nxt.x, nxt.y}; // current row of pyramid level s-1 (starts as x)
        if (h + 1 < rend) {           // prefetch next row (uniform branch)
            px += rstride;
            if (colok) nxt = *(const float2*)px;
        }
        if (h < row0 + STRIP) { // scale 1: output row h is owned
            acc[0][0] = fmaf(cp[0], m[0], acc[0][0]);
            acc[0][1] = fmaf(cp[1], m[0], acc[0][1]);
        }
#pragma unroll
        for (int s = 2; s <= NS; ++s) {
            float vmax[2], vn[2];
#pragma unroll
            for (int c = 0; c < 2; ++c) vmax[c] = fmaxf(prev[s - 2][c], cp[c]); // vertical 2-max
#pragma unroll
            for (int c = 0; c < 2; ++c) vn[c] = __shfl_down(vmax[c], 1);        // j+1 neighbor
#pragma unroll
            for (int c = 0; c < 2; ++c) prev[s - 2][c] = cp[c];                 // rotate history
#pragma unroll
            for (int c = 0; c < 2; ++c) cp[c] = fmaxf(vmax[c], vn[c]);          // P_s row h-s+1
            const int r = h - s + 1;
            if (r >= row0 && r < row0 + STRIP) { // uniform row-ownership branch
#pragma unroll
                for (int c = 0; c < 2; ++c) acc[s - 1][c] = fmaf(cp[c], m[s - 1], acc[s - 1][c]);
            }
        }
    }

    // Wave butterfly reduction; lane 0 atomics the 20 partials.
#pragma unroll
    for (int s = 0; s < NS; ++s) {
#pragma unroll
        for (int c = 0; c < 2; ++c) {
            float v = acc[s][c];
#pragma unroll
            for (int off = 32; off > 0; off >>= 1) v += __shfl_xor(v, off);
            if (lane == 0) atomicAdd(&out[((size_t)b * DCH + ch + c) * NS + s], v);
        }
    }
}

extern "C" void kernel_launch(void* const* d_in, const int* in_sizes, int n_in,
                              void* d_out, int out_size, void* d_ws, size_t ws_size,
                              hipStream_t stream) {
    const float* x = (const float*)d_in[0];
    float* out = (float*)d_out;
    const int nblk = (out_size + 255) / 256;
    zero_kernel<<<nblk, 256, 0, stream>>>(out, out_size);
    pool_kernel<<<BB * CG * NSEG * NSTRIP, 256, 0, stream>>>(x, out);
    finalize_kernel<<<nblk, 256, 0, stream>>>(out, out_size);
}

// Round 3
// 235.197 us; speedup vs baseline: 1.0441x; 1.0441x over previous
//
#include <hip/hip_runtime.h>

// x [B=8, H=224, W=224, D=8, C=8] fp32 (64 ch innermost), out [8,8,8,10] fp32.
// out[b,d,c,s-1] = relu( sum over valid (r,j) of max_{s x s window}(x) ) + 1.
#define BB 8
#define HH 224
#define WW 224
#define DCH 64
#define NS 10
#define SEG_OUT 55 // output cols per wave (64 lanes - 9 halo)
#define NSEG 5
#define STRIP 28   // output rows per strip
#define NSTRIP 8
#define NCG 4      // channel groups of 16; block = 8 waves x 2ch = 16 ch = one 64B line

__global__ void zero_kernel(float* out, int n) {
    int i = blockIdx.x * blockDim.x + threadIdx.x;
    if (i < n) out[i] = 0.0f;
}

__global__ void finalize_kernel(float* out, int n) {
    int i = blockIdx.x * blockDim.x + threadIdx.x;
    if (i < n) out[i] = fmaxf(out[i], 0.0f) + 1.0f;
}

// Doubling pyramid per (lane=col, 2ch):
//   chain (this row, depth 3): P2=rows[h-1,h], P4=rows[h-3,h], P8=rows[h-7,h]
//   combos (deferred, prev-iteration rings only, independent): s=3,5,6,7,9,10.
// Grid = 8b * 4cg * 5seg * 8strip = 1280 blocks of 512.
__global__ __launch_bounds__(512, 4) void pool_kernel(const float* __restrict__ x,
                                                      float* __restrict__ out) {
    const int bid = blockIdx.x;
    const int cg  = bid & (NCG - 1);
    int rest = bid >> 2;
    const int ws = rest % NSEG; rest /= NSEG;
    const int hs = rest % NSTRIP;
    const int b  = rest / NSTRIP;

    const int wave = threadIdx.x >> 6;
    const int lane = threadIdx.x & 63;
    const int ch   = cg * 16 + wave * 2;   // 2 channels per lane (float2)
    const int col  = ws * SEG_OUT + lane;
    const int row0 = hs * STRIP;
    const int hend = row0 + STRIP;                 // exclusive owned-row bound
    const int hstop = min(hend + (NS - 1), HH);    // inclusive final (flush) iter

    // Column-validity masks (0/1), applied via fma; all data stays finite
    // (pads load 0, rings init 0, shuffle wrap pulls finite data into masked lanes).
    float m[NS];
#pragma unroll
    for (int s = 1; s <= NS; ++s)
        m[s - 1] = (lane < SEG_OUT && col <= WW - s) ? 1.0f : 0.0f;

    float xprev[2] = {0.f, 0.f};                       // x row h-1
    float p2[2][2] = {{0.f,0.f},{0.f,0.f}};            // P2 rows h-2, h-3
    float p4[4][2] = {{0.f,0.f},{0.f,0.f},{0.f,0.f},{0.f,0.f}}; // P4 rows h-4..h-7
    float p8[3][2] = {{0.f,0.f},{0.f,0.f},{0.f,0.f}};  // P8 rows h-8..h-10
    float acc[NS][2];
#pragma unroll
    for (int s = 0; s < NS; ++s) { acc[s][0] = 0.f; acc[s][1] = 0.f; }

    const bool colok = (col < WW);
    const float* px = x + (((size_t)(b * HH + row0) * WW + col) * DCH + ch);
    const size_t rstride = (size_t)WW * DCH;
    float2 nxt = colok ? *(const float2*)px : make_float2(0.f, 0.f);

    for (int h = row0; h <= hstop; ++h) {
        const float cur0 = nxt.x, cur1 = nxt.y;      // x row h (0 on flush iter)
        if (h + 1 < hstop) {                         // prefetch x row h+1
            px += rstride;
            nxt = colok ? *(const float2*)px : make_float2(0.f, 0.f);
        } else {
            nxt = make_float2(0.f, 0.f);
        }

        // ---------- combos: scale s at output row r = h - s (prev rings only)
        // s=3: P2 rows h-3 (p2[1]), h-2 (p2[0]); col reach +1
        {
            float U0 = fmaxf(p2[0][0], p2[1][0]);
            float U1 = fmaxf(p2[0][1], p2[1][1]);
            float P0 = fmaxf(U0, __shfl_down(U0, 1));
            float P1 = fmaxf(U1, __shfl_down(U1, 1));
            float g = (h - 3 >= row0 && h - 3 < hend) ? m[2] : 0.f;
            acc[2][0] = fmaf(P0, g, acc[2][0]);
            acc[2][1] = fmaf(P1, g, acc[2][1]);
        }
        // s=5: P4 rows h-5 (p4[1]), h-4 (p4[0]); col reach +1
        {
            float U0 = fmaxf(p4[0][0], p4[1][0]);
            float U1 = fmaxf(p4[0][1], p4[1][1]);
            float P0 = fmaxf(U0, __shfl_down(U0, 1));
            float P1 = fmaxf(U1, __shfl_down(U1, 1));
            float g = (h - 5 >= row0 && h - 5 < hend) ? m[4] : 0.f;
            acc[4][0] = fmaf(P0, g, acc[4][0]);
            acc[4][1] = fmaf(P1, g, acc[4][1]);
        }
        // s=6: P4 rows h-6 (p4[2]), h-4 (p4[0]); col reach +2
        {
            float U0 = fmaxf(p4[0][0], p4[2][0]);
            float U1 = fmaxf(p4[0][1], p4[2][1]);
            float P0 = fmaxf(U0, __shfl_down(U0, 2));
            float P1 = fmaxf(U1, __shfl_down(U1, 2));
            float g = (h - 6 >= row0 && h - 6 < hend) ? m[5] : 0.f;
            acc[5][0] = fmaf(P0, g, acc[5][0]);
            acc[5][1] = fmaf(P1, g, acc[5][1]);
        }
        // s=7: P4 rows h-7 (p4[3]), h-4 (p4[0]); col reach +3
        {
            float U0 = fmaxf(p4[0][0], p4[3][0]);
            float U1 = fmaxf(p4[0][1], p4[3][1]);
            float P0 = fmaxf(U0, __shfl_down(U0, 3));
            float P1 = fmaxf(U1, __shfl_down(U1, 3));
            float g = (h - 7 >= row0 && h - 7 < hend) ? m[6] : 0.f;
            acc[6][0] = fmaf(P0, g, acc[6][0]);
            acc[6][1] = fmaf(P1, g, acc[6][1]);
        }
        // s=9: P8 rows h-9 (p8[1]), h-8 (p8[0]); col reach +1
        {
            float U0 = fmaxf(p8[0][0], p8[1][0]);
            float U1 = fmaxf(p8[0][1], p8[1][1]);
            float P0 = fmaxf(U0, __shfl_down(U0, 1));
            float P1 = fmaxf(U1, __shfl_down(U1, 1));
            float g = (h - 9 >= row0 && h - 9 < hend) ? m[8] : 0.f;
            acc[8][0] = fmaf(P0, g, acc[8][0]);
            acc[8][1] = fmaf(P1, g, acc[8][1]);
        }
        // s=10: P8 rows h-10 (p8[2]), h-8 (p8[0]); col reach +2
        {
            float U0 = fmaxf(p8[0][0], p8[2][0]);
            float U1 = fmaxf(p8[0][1], p8[2][1]);
            float P0 = fmaxf(U0, __shfl_down(U0, 2));
            float P1 = fmaxf(U1, __shfl_down(U1, 2));
            float g = (h - 10 >= row0 && h - 10 < hend) ? m[9] : 0.f;
            acc[9][0] = fmaf(P0, g, acc[9][0]);
            acc[9][1] = fmaf(P1, g, acc[9][1]);
        }

        // ---------- chain (depth-3 dependent shuffles)
        const bool hin = (h < HH);
        float T0 = fmaxf(xprev[0], cur0);
        float T1 = fmaxf(xprev[1], cur1);
        float P2n0 = fmaxf(T0, __shfl_down(T0, 1));   // P2 row h-1
        float P2n1 = fmaxf(T1, __shfl_down(T1, 1));
        {
            float g = (hin && h - 1 >= row0 && h - 1 < hend) ? m[1] : 0.f;
            acc[1][0] = fmaf(P2n0, g, acc[1][0]);
            acc[1][1] = fmaf(P2n1, g, acc[1][1]);
        }
        {
            float g = (hin && h >= row0 && h < hend) ? m[0] : 0.f; // s=1, row h
            acc[0][0] = fmaf(cur0, g, acc[0][0]);
            acc[0][1] = fmaf(cur1, g, acc[0][1]);
        }
        float V0 = fmaxf(P2n0, p2[1][0]);             // rows h-3..h
        float V1 = fmaxf(P2n1, p2[1][1]);
        float P4n0 = fmaxf(V0, __shfl_down(V0, 2));   // P4 row h-3
        float P4n1 = fmaxf(V1, __shfl_down(V1, 2));
        {
            float g = (hin && h - 3 >= row0 && h - 3 < hend) ? m[3] : 0.f;
            acc[3][0] = fmaf(P4n0, g, acc[3][0]);
            acc[3][1] = fmaf(P4n1, g, acc[3][1]);
        }
        float W0 = fmaxf(P4n0, p4[3][0]);             // rows h-7..h
        float W1 = fmaxf(P4n1, p4[3][1]);
        float P8n0 = fmaxf(W0, __shfl_down(W0, 4));   // P8 row h-7
        float P8n1 = fmaxf(W1, __shfl_down(W1, 4));
        {
            float g = (hin && h - 7 >= row0 && h - 7 < hend) ? m[7] : 0.f;
            acc[7][0] = fmaf(P8n0, g, acc[7][0]);
            acc[7][1] = fmaf(P8n1, g, acc[7][1]);
        }

        // ---------- rotate rings
        p2[1][0] = p2[0][0]; p2[1][1] = p2[0][1];
        p2[0][0] = P2n0;     p2[0][1] = P2n1;
        p4[3][0] = p4[2][0]; p4[3][1] = p4[2][1];
        p4[2][0] = p4[1][0]; p4[2][1] = p4[1][1];
        p4[1][0] = p4[0][0]; p4[1][1] = p4[0][1];
        p4[0][0] = P4n0;     p4[0][1] = P4n1;
        p8[2][0] = p8[1][0]; p8[2][1] = p8[1][1];
        p8[1][0] = p8[0][0]; p8[1][1] = p8[0][1];
        p8[0][0] = P8n0;     p8[0][1] = P8n1;
        xprev[0] = cur0;     xprev[1] = cur1;
    }

    // Wave butterfly reduction; lane 0 atomics 20 partials.
#pragma unroll
    for (int s = 0; s < NS; ++s) {
#pragma unroll
        for (int c = 0; c < 2; ++c) {
            float v = acc[s][c];
#pragma unroll
            for (int off = 32; off > 0; off >>= 1) v += __shfl_xor(v, off);
            if (lane == 0) atomicAdd(&out[((size_t)b * DCH + ch + c) * NS + s], v);
        }
    }
}

extern "C" void kernel_launch(void* const* d_in, const int* in_sizes, int n_in,
                              void* d_out, int out_size, void* d_ws, size_t ws_size,
                              hipStream_t stream) {
    const float* x = (const float*)d_in[0];
    float* out = (float*)d_out;
    const int nblk = (out_size + 255) / 256;
    zero_kernel<<<nblk, 256, 0, stream>>>(out, out_size);
    pool_kernel<<<BB * NCG * NSEG * NSTRIP, 512, 0, stream>>>(x, out);
    finalize_kernel<<<nblk, 256, 0, stream>>>(out, out_size);
}